// Round 7
// baseline (4514.136 us; speedup 1.0000x reference)
//
#include <hip/hip_runtime.h>
#include <hip/hip_bf16.h>

// PBRNN LSTM: B=64, S=512, D=544, H=1024. out = [h_n; c_n] fp32 [2,64,1024].
//
// Round 7: intra-XCD L2 h-exchange + precomputed x-projection.
//  - grid 512, 2 blocks/CU (launch_bounds(256,2) caps VGPR<=256 so all 512
//    are co-resident). machine = blockIdx&7 -> one XCD under round-robin.
//  - h stores: plain global_store (lands in shared XCD L2) + agent store
//    (LIC). h polls: sc0-only asm loads (bypass L1, hit L2, ~200cyc);
//    after 3 stale rounds escalate to agent loads (LIC) -> correct under
//    ANY block->XCD mapping (G16-safe), fast when round-robin holds.
//  - xp = X.Wih^T + biases precomputed by chunked GEMM kernels alternating
//    with chunked LSTM launches (frees ~100 VGPRs; critical loop reads 8B
//    of xp per thread per step). Chunk adapts to ws_size.

#define B_  64
#define S_  512
#define D_  544
#define H_  1024

typedef __attribute__((ext_vector_type(8))) short bf16x8;
typedef __attribute__((ext_vector_type(4))) float f32x4;
typedef __attribute__((ext_vector_type(4))) unsigned int u32x4;

__device__ inline ushort f2b(float x){
  unsigned u = __float_as_uint(x);
  u = (u + 0x7FFFu + ((u >> 16) & 1u)) >> 16;   // RNE
  return (ushort)u;
}
__device__ inline bf16x8 pack8(float4 a, float4 b){
  bf16x8 r;
  r[0]=(short)f2b(a.x); r[1]=(short)f2b(a.y); r[2]=(short)f2b(a.z); r[3]=(short)f2b(a.w);
  r[4]=(short)f2b(b.x); r[5]=(short)f2b(b.y); r[6]=(short)f2b(b.z); r[7]=(short)f2b(b.w);
  return r;
}
__device__ inline unsigned long long ld64a(const unsigned long long* q){
  return __hip_atomic_load(q, __ATOMIC_RELAXED, __HIP_MEMORY_SCOPE_AGENT);
}
__device__ inline float sigm(float x){ return __builtin_amdgcn_rcpf(1.f + __expf(-x)); }
__device__ inline float tanh_(float x){ return 1.f - 2.f*__builtin_amdgcn_rcpf(1.f + __expf(2.f*x)); }
__device__ inline float b2f(ushort u){ return __uint_as_float(((unsigned)u) << 16); }

__global__ void cvt_bf16(const float* __restrict__ x, ushort* __restrict__ o, int n4){
  int i = blockIdx.x*256 + threadIdx.x;
  if (i >= n4) return;
  float4 v = ((const float4*)x)[i];
  ushort4 r; r.x=f2b(v.x); r.y=f2b(v.y); r.z=f2b(v.z); r.w=f2b(v.w);
  ((ushort4*)o)[i] = r;
}

// ---------------- XP GEMM: xp[t][b][4H] = X.Wih^T + (bih+bhh), blocked ----
// xpb layout (ushort): (((mach*64+cg)*C + ct)*8 + bl)*64 + uu*4 + g
template<bool XB>
__global__ void xp_gemm(const float* __restrict__ X, const ushort* __restrict__ Xbb,
                        const ushort* __restrict__ Wihb,
                        const float* __restrict__ bih, const float* __restrict__ bhh,
                        ushort* __restrict__ xpb, int t0, int C, int lg){
  const int tid = threadIdx.x, w = tid>>6, lane = tid&63;
  const int c16 = lane&15, quad = lane>>4;
  const int mach = blockIdx.x & 7;
  const int idx2 = blockIdx.x >> 3;
  const int cg   = idx2 & 63;
  const int rblk = idx2 >> 6;

  const int r  = rblk*64 + w*16 + c16;      // local r within machine (8 b x C t)
  const int bl = r >> lg, ct = r & (C-1);
  const size_t rowg = ((size_t)(mach*8 + bl)*S_ + (size_t)(t0 + ct));

  f32x4 acc[4];
  #pragma unroll
  for (int mt=0; mt<4; ++mt) acc[mt] = (f32x4){0.f,0.f,0.f,0.f};

  for (int it=0; it<17; ++it){
    bf16x8 bfr;
    if (XB){
      bfr = *(const bf16x8*)(Xbb + rowg*D_ + it*32 + quad*8);
    } else {
      const float4* p = (const float4*)(X + rowg*D_ + it*32 + quad*8);
      bfr = pack8(p[0], p[1]);
    }
    #pragma unroll
    for (int mt=0; mt<4; ++mt){
      bf16x8 afr = *(const bf16x8*)(Wihb + (size_t)(mt*H_ + cg*16 + c16)*D_ + it*32 + quad*8);
      acc[mt] = __builtin_amdgcn_mfma_f32_16x16x32_bf16(afr, bfr, acc[mt], 0,0,0);
    }
  }

  __shared__ ushort lds_ep[4][16][64];
  #pragma unroll
  for (int mt=0; mt<4; ++mt)
    #pragma unroll
    for (int rg=0; rg<4; ++rg){
      int uu = quad*4 + rg;
      int j  = mt*H_ + cg*16 + uu;
      lds_ep[w][c16][uu*4 + mt] = f2b(acc[mt][rg] + bih[j] + bhh[j]);
    }
  __syncthreads();

  {
    const int rl = lane >> 2, ck = lane & 3;
    const int r2 = rblk*64 + w*16 + rl;
    const int bl2 = r2 >> lg, ct2 = r2 & (C-1);
    const uint4* src = (const uint4*)&lds_ep[w][rl][ck*16];
    uint4* dst = (uint4*)(xpb + ((((size_t)(mach*64+cg)*C + ct2)*8 + bl2)*64 + ck*16));
    dst[0] = src[0];
    dst[1] = src[1];
  }
}

// ---------------- persistent LSTM over a chunk of C steps ----------------
__global__ __launch_bounds__(256,2) void lstm_persist(
    const ushort* __restrict__ Whhb,
    const ushort* __restrict__ xpb,
    unsigned* thbuf,        // [2 slot][8 mach][8192 words] tagged h
    float* cws,             // [8][64][128] c-state carry
    float* __restrict__ out, int t0, int C)
{
  const int tid  = threadIdx.x;
  const int wave = tid >> 6;
  const int lane = tid & 63;
  const int c16  = lane & 15;
  const int quad = lane >> 4;
  const int mach = blockIdx.x & 7;
  const int cg   = blockIdx.x >> 3;

  __shared__ float gates_s[2][4][64][9];

  // W_hh A-fragments (VGPR-pinned, bf16): 4 gate tiles x 8 K-iters (K-quarter)
  bf16x8 whhf[4][8];
  #pragma unroll
  for (int mt=0; mt<4; ++mt)
    #pragma unroll
    for (int i=0; i<8; ++i)
      whhf[mt][i] = *(const bf16x8*)(Whhb + (size_t)(mt*H_ + cg*16 + c16)*H_
                                     + wave*256 + i*32 + quad*8);

  const int uu = tid & 15, nn = (tid >> 4) & 7;
  float cst = 0.f;
  if (t0 > 0 && tid < 128) cst = cws[(mach*64+cg)*128 + tid];

  const ushort* xq = xpb + (size_t)(mach*64+cg)*C*512;
  ushort4 xpv = {0,0,0,0};
  if (tid < 128) xpv = *(const ushort4*)(xq + (size_t)nn*64 + uu*4);

  // poll base byte offset within machine region (frag i adds i*1024 B)
  const unsigned lo_off = ((unsigned)((wave*32 + quad)*64 + (c16&7)*8)) * 4u;

  for (int t = t0; t < t0 + C; ++t){
    const char* hp = (const char*)(thbuf + ((size_t)((t&1)*8 + mach) * 8192)) + lo_off;
    unsigned*   hn = thbuf + ((size_t)(((t+1)&1)*8 + mach) * 8192);

    u32x4 q[16];
    const unsigned T = ((unsigned)t & 0xffffu) << 16;

    // ---- poll: up to 3 plain sc0 rounds (XCD-L2 path), then agent ----
    bool good = false;
    for (int rnd = 0; rnd < 3 && !good; ++rnd){
      const char* b1 = hp + 4096;
      asm volatile(
        "global_load_dwordx4 %0,  %16, off sc0\n\t"
        "global_load_dwordx4 %1,  %16, off offset:16 sc0\n\t"
        "global_load_dwordx4 %2,  %16, off offset:1024 sc0\n\t"
        "global_load_dwordx4 %3,  %16, off offset:1040 sc0\n\t"
        "global_load_dwordx4 %4,  %16, off offset:2048 sc0\n\t"
        "global_load_dwordx4 %5,  %16, off offset:2064 sc0\n\t"
        "global_load_dwordx4 %6,  %16, off offset:3072 sc0\n\t"
        "global_load_dwordx4 %7,  %16, off offset:3088 sc0\n\t"
        "global_load_dwordx4 %8,  %17, off sc0\n\t"
        "global_load_dwordx4 %9,  %17, off offset:16 sc0\n\t"
        "global_load_dwordx4 %10, %17, off offset:1024 sc0\n\t"
        "global_load_dwordx4 %11, %17, off offset:1040 sc0\n\t"
        "global_load_dwordx4 %12, %17, off offset:2048 sc0\n\t"
        "global_load_dwordx4 %13, %17, off offset:2064 sc0\n\t"
        "global_load_dwordx4 %14, %17, off offset:3072 sc0\n\t"
        "global_load_dwordx4 %15, %17, off offset:3088 sc0\n\t"
        "s_waitcnt vmcnt(0)"
        : "=v"(q[0]), "=v"(q[1]), "=v"(q[2]),  "=v"(q[3]),
          "=v"(q[4]), "=v"(q[5]), "=v"(q[6]),  "=v"(q[7]),
          "=v"(q[8]), "=v"(q[9]), "=v"(q[10]), "=v"(q[11]),
          "=v"(q[12]),"=v"(q[13]),"=v"(q[14]), "=v"(q[15])
        : "v"(hp), "v"(b1)
        : "memory");
      unsigned bad = 0u;
      #pragma unroll
      for (int i=0; i<16; ++i)
        bad |= ((q[i].x^T)|(q[i].y^T)|(q[i].z^T)|(q[i].w^T)) & 0xffff0000u;
      good = __all(bad == 0u);
    }
    if (!good){
      // escalation: agent (LIC-authoritative) per-chunk retries
      unsigned stale = 0u;
      #pragma unroll
      for (int i=0; i<16; ++i){
        unsigned d = ((q[i].x^T)|(q[i].y^T)|(q[i].z^T)|(q[i].w^T)) & 0xffff0000u;
        stale |= (d != 0u) ? (1u<<i) : 0u;
      }
      int guard = 0;
      while (__any(stale != 0u)){
        unsigned ns = 0u;
        #pragma unroll
        for (int i=0; i<16; ++i){
          if (stale & (1u<<i)){
            const unsigned long long* pq =
              (const unsigned long long*)(hp + (i>>1)*1024 + (i&1)*16);
            unsigned long long a = ld64a(pq), b = ld64a(pq+1);
            q[i].x=(unsigned)a; q[i].y=(unsigned)(a>>32);
            q[i].z=(unsigned)b; q[i].w=(unsigned)(b>>32);
            unsigned d = ((q[i].x^T)|(q[i].y^T)|(q[i].z^T)|(q[i].w^T)) & 0xffff0000u;
            ns |= (d != 0u) ? (1u<<i) : 0u;
          }
        }
        stale = ns;
        if (++guard > 8192) break;        // visible failure, never a hang
        __builtin_amdgcn_s_sleep(1);
      }
    }

    // ---- extract (v_perm) + hh MFMA ----
    f32x4 acc[4];
    #pragma unroll
    for (int mt=0; mt<4; ++mt) acc[mt] = (f32x4){0.f,0.f,0.f,0.f};
    #pragma unroll
    for (int f=0; f<8; ++f){
      union { unsigned u[4]; bf16x8 v8; } eb;
      eb.u[0] = __builtin_amdgcn_perm(q[2*f].y,   q[2*f].x,   0x05040100u);
      eb.u[1] = __builtin_amdgcn_perm(q[2*f].w,   q[2*f].z,   0x05040100u);
      eb.u[2] = __builtin_amdgcn_perm(q[2*f+1].y, q[2*f+1].x, 0x05040100u);
      eb.u[3] = __builtin_amdgcn_perm(q[2*f+1].w, q[2*f+1].z, 0x05040100u);
      #pragma unroll
      for (int mt=0; mt<4; ++mt)
        acc[mt] = __builtin_amdgcn_mfma_f32_16x16x32_bf16(whhf[mt][f], eb.v8, acc[mt], 0,0,0);
    }

    // ---- per-wave partials -> LDS (ping-pong, 1 barrier/step) ----
    if (c16 < 8){
      #pragma unroll
      for (int mt=0; mt<4; ++mt)
        #pragma unroll
        for (int rg=0; rg<4; ++rg)
          gates_s[t&1][wave][mt*16 + quad*4 + rg][c16] = acc[mt][rg];
    }
    __syncthreads();

    // ---- update + dual h store (plain->L2, agent->LIC) ----
    if (tid < 128){
      float gsum[4];
      #pragma unroll
      for (int g=0; g<4; ++g){
        float s;
        s  = gates_s[t&1][0][g*16+uu][nn];
        s += gates_s[t&1][1][g*16+uu][nn];
        s += gates_s[t&1][2][g*16+uu][nn];
        s += gates_s[t&1][3][g*16+uu][nn];
        gsum[g] = s;
      }
      gsum[0] += b2f(xpv.x); gsum[1] += b2f(xpv.y);
      gsum[2] += b2f(xpv.z); gsum[3] += b2f(xpv.w);
      float iv = sigm(gsum[0]), fv = sigm(gsum[1]), gv = tanh_(gsum[2]), ov = sigm(gsum[3]);
      float cn = fv*cst + iv*gv;
      cst = cn;
      float hv = ov*tanh_(cn);
      unsigned word = (((unsigned)(t+1)) << 16) | (unsigned)f2b(hv);
      unsigned* wp = hn + (cg*2 + (uu>>3))*64 + nn*8 + (uu&7);
      asm volatile("global_store_dword %0, %1, off" :: "v"(wp), "v"(word) : "memory");
      __hip_atomic_store(wp, word, __ATOMIC_RELAXED, __HIP_MEMORY_SCOPE_AGENT);
      if (t == S_-1){
        out[(mach*8+nn)*H_ + cg*16 + uu]          = hv;
        out[B_*H_ + (mach*8+nn)*H_ + cg*16 + uu]  = cn;
      }
      // prefetch next step's xp
      int ctn = t - t0 + 1; if (ctn >= C) ctn = C-1;
      xpv = *(const ushort4*)(xq + (size_t)ctn*512 + (size_t)nn*64 + uu*4);
    }
  }

  if (tid < 128) cws[(mach*64+cg)*128 + tid] = cst;
}

extern "C" void kernel_launch(void* const* d_in, const int* in_sizes, int n_in,
                              void* d_out, int out_size, void* d_ws, size_t ws_size,
                              hipStream_t stream) {
  const float* X   = (const float*)d_in[0];
  const float* Wih = (const float*)d_in[1];
  const float* Whh = (const float*)d_in[2];
  const float* bih = (const float*)d_in[3];
  const float* bhh = (const float*)d_in[4];
  float* out = (float*)d_out;

  // ws layout (bytes):
  //   0        thbuf   524288   (2 x 8 x 8192 x 4)
  //   524288   cws     262144
  //   786432   Wihb    4456448  (4096 x 544 bf16)
  //   5242880  Whhb    8388608  (4096 x 1024 bf16)
  //   13631488 xpb     524288*C
  //   +        Xb      35651584 (optional, 64*512*544 bf16)
  char* ws = (char*)d_ws;
  const size_t OFF_TH = 0, OFF_CWS = 524288, OFF_WIH = 786432, OFF_WHH = 5242880;
  const size_t OFF_XPB = 13631488;
  const size_t XB_BYTES = 35651584;

  int C = 0, lg = 0, useXb = 0;
  if      (ws_size >= OFF_XPB + 524288ull*64 + XB_BYTES){ C=64; lg=6; useXb=1; }
  else if (ws_size >= OFF_XPB + 524288ull*32 + XB_BYTES){ C=32; lg=5; useXb=1; }
  else if (ws_size >= OFF_XPB + 524288ull*16 + XB_BYTES){ C=16; lg=4; useXb=1; }
  else if (ws_size >= OFF_XPB + 524288ull*32)           { C=32; lg=5; useXb=0; }
  else if (ws_size >= OFF_XPB + 524288ull*16)           { C=16; lg=4; useXb=0; }
  else return;   // insufficient scratch: fail visibly

  unsigned* thbuf = (unsigned*)(ws + OFF_TH);
  float*    cws   = (float*)(ws + OFF_CWS);
  ushort*   Wihb  = (ushort*)(ws + OFF_WIH);
  ushort*   Whhb  = (ushort*)(ws + OFF_WHH);
  ushort*   xpb   = (ushort*)(ws + OFF_XPB);
  ushort*   Xb    = (ushort*)(ws + OFF_XPB + 524288ull*C);

  hipMemsetAsync(d_ws, 0, OFF_WIH, stream);   // zero thbuf (tags) + cws

  cvt_bf16<<<(4096*544/4 + 255)/256, 256, 0, stream>>>(Wih, Wihb, 4096*544/4);
  cvt_bf16<<<(4096*1024/4 + 255)/256, 256, 0, stream>>>(Whh, Whhb, 4096*1024/4);
  if (useXb)
    cvt_bf16<<<(B_*S_*D_/4 + 255)/256, 256, 0, stream>>>(X, Xb, B_*S_*D_/4);

  const int nch = S_ / C;
  for (int ch = 0; ch < nch; ++ch){
    const int t0 = ch * C;
    if (useXb)
      xp_gemm<true ><<<64*C, 256, 0, stream>>>(X, Xb, Wihb, bih, bhh, xpb, t0, C, lg);
    else
      xp_gemm<false><<<64*C, 256, 0, stream>>>(X, Xb, Wihb, bih, bhh, xpb, t0, C, lg);
    lstm_persist<<<512, 256, 0, stream>>>(Whhb, xpb, thbuf, cws, out, t0, C);
  }
}

// Round 8
// 3056.914 us; speedup vs baseline: 1.4767x; 1.4767x over previous
//
#include <hip/hip_runtime.h>
#include <hip/hip_bf16.h>

// PBRNN LSTM: B=64, S=512, D=544, H=1024. out = [h_n; c_n] fp32 [2,64,1024].
//
// Round 8: round-6 structure (best known: 2342us) + pipelined poll issue.
//  - Tagged-word self-timed h exchange via LIC (agent-scope), 256 blocks =
//    64 cg x 4 bg, W in VGPRs, XCD-affinity swizzle, parallel retry rounds.
//  - NEW: next-step poll loads issued immediately after the h store, BEFORE
//    xp_mfma/ldx -> first poll RT overlaps xp compute + peer publication.
//  - NEW: v_perm_b32 extraction (halves tag-strip VALU).
//  - (R7 lesson: dual plain+agent store self-defeats -- agent store
//    invalidates the L2 line the plain store wrote. Reverted.)

#define B_  64
#define S_  512
#define D_  544
#define H_  1024
#define CG_ 64
#define BG_ 4
#define GRID_ (CG_*BG_)

typedef __attribute__((ext_vector_type(8))) short bf16x8;
typedef __attribute__((ext_vector_type(4))) float f32x4;

__device__ inline ushort f2b(float x){
  unsigned u = __float_as_uint(x);
  u = (u + 0x7FFFu + ((u >> 16) & 1u)) >> 16;   // RNE
  return (ushort)u;
}

__device__ inline bf16x8 pack8(float4 a, float4 b){
  bf16x8 r;
  r[0]=(short)f2b(a.x); r[1]=(short)f2b(a.y); r[2]=(short)f2b(a.z); r[3]=(short)f2b(a.w);
  r[4]=(short)f2b(b.x); r[5]=(short)f2b(b.y); r[6]=(short)f2b(b.z); r[7]=(short)f2b(b.w);
  return r;
}

__device__ inline unsigned long long ld64a(const unsigned long long* q){
  return __hip_atomic_load(q, __ATOMIC_RELAXED, __HIP_MEMORY_SCOPE_AGENT);
}

__device__ inline float sigm(float x){ return __builtin_amdgcn_rcpf(1.f + __expf(-x)); }
__device__ inline float tanh_(float x){ return 1.f - 2.f*__builtin_amdgcn_rcpf(1.f + __expf(2.f*x)); }

__global__ void cvt_x(const float* __restrict__ x, ushort* __restrict__ xb, int n4){
  int i = blockIdx.x*256 + threadIdx.x;
  if (i >= n4) return;
  float4 v = ((const float4*)x)[i];
  ushort4 o;
  o.x=f2b(v.x); o.y=f2b(v.y); o.z=f2b(v.z); o.w=f2b(v.w);
  ((ushort4*)xb)[i] = o;
}

__global__ __launch_bounds__(256,1) void lstm_persist(
    const float* __restrict__ Wih, const float* __restrict__ Whh,
    const float* __restrict__ bih, const float* __restrict__ bhh,
    const ushort* __restrict__ Xb,
    unsigned* thbuf,       // [2][BG_][CG_][16 n][16 k] tagged words, pre-zeroed
    float* __restrict__ out)
{
  const int tid  = threadIdx.x;
  const int wave = tid >> 6;          // K-quarter for W_hh
  const int lane = tid & 63;
  const int c16  = lane & 15;
  const int quad = lane >> 4;
  // XCD-affinity swizzle: XCD = blockIdx%8 (round-robin dispatch)
  const int bg   = (blockIdx.x & 7) >> 1;
  const int cg   = ((blockIdx.x >> 3) << 1) | (blockIdx.x & 1);

  // double-buffered per-wave gate partials
  __shared__ float gates_s[2][4][64][17];

  // ---- W_hh A-fragments (VGPR-pinned): 4 M-tiles (gates i,f,g,o) x 8 K-iters
  bf16x8 whhf[4][8];
  #pragma unroll
  for (int mt = 0; mt < 4; ++mt){
    const size_t grow = (size_t)(mt*H_ + cg*16 + c16);
    #pragma unroll
    for (int i = 0; i < 8; ++i){
      int k = wave*256 + i*32 + quad*8;
      const float4* p = (const float4*)(Whh + grow*H_ + k);
      whhf[mt][i] = pack8(p[0], p[1]);
    }
  }
  // ---- W_ih A-fragments: K-iters it = wave, wave+4, ... < 17 ----
  bf16x8 wihf[4][5];
  #pragma unroll
  for (int mt = 0; mt < 4; ++mt){
    const size_t grow = (size_t)(mt*H_ + cg*16 + c16);
    #pragma unroll
    for (int ii = 0; ii < 5; ++ii){
      int it = wave + 4*ii;
      if (it < 17){
        int k = it*32 + quad*8;
        const float4* p = (const float4*)(Wih + grow*D_ + k);
        wihf[mt][ii] = pack8(p[0], p[1]);
      }
    }
  }

  // ---- update mapping: thread owns (batch nn, col uu) ----
  const int uu = tid & 15;
  const int nn = tid >> 4;
  float bsum[4];
  #pragma unroll
  for (int g = 0; g < 4; ++g)
    bsum[g] = bih[g*H_ + cg*16 + uu] + bhh[g*H_ + cg*16 + uu];
  float cstate = 0.f;

  f32x4 acc[4];      // [gate tile]
  bf16x8 xraw[5];    // raw X fragments for the NEXT xp_gemm (preloaded)
  unsigned long long q[8][4];   // in-flight poll buffer (lives across steps)

  auto zacc = [&]{
    #pragma unroll
    for (int mt = 0; mt < 4; ++mt) acc[mt] = (f32x4){0.f,0.f,0.f,0.f};
  };
  auto ldx = [&](int t){            // issue raw X loads (no compute dep)
    if (t >= S_) t = S_-1;          // clamp: avoid OOB on the tail prefetch
    #pragma unroll
    for (int ii = 0; ii < 5; ++ii){
      int it = wave + 4*ii;
      if (it < 17)
        xraw[ii] = *(const bf16x8*)(Xb + ((size_t)(bg*16 + c16)*S_ + t)*D_ + it*32 + quad*8);
    }
  };
  auto xp_mfma = [&]{               // consume xraw (loads long since landed)
    #pragma unroll
    for (int ii = 0; ii < 5; ++ii){
      int it = wave + 4*ii;
      if (it < 17){
        #pragma unroll
        for (int mt = 0; mt < 4; ++mt)
          acc[mt] = __builtin_amdgcn_mfma_f32_16x16x32_bf16(wihf[mt][ii], xraw[ii], acc[mt], 0,0,0);
      }
    }
  };

  // consumer fragment word offset (excluding the i*512 term):
  // slab = bg*64 + wave*16 + i*2 + (quad>>1); word = slab*256 + c16*16 + (quad&1)*8
  const int obase = (bg*64 + wave*16 + (quad>>1))*256 + c16*16 + (quad&1)*8;

  auto issue_poll = [&](const unsigned* hp){
    #pragma unroll
    for (int i = 0; i < 8; ++i){
      const unsigned long long* p = (const unsigned long long*)(hp + obase + i*512);
      q[i][0] = ld64a(p);   q[i][1] = ld64a(p+1);
      q[i][2] = ld64a(p+2); q[i][3] = ld64a(p+3);
    }
  };

  // prologue: xp(0) computed, X(1) in flight, poll(0) in flight
  ldx(0);
  zacc();
  xp_mfma();
  ldx(1);
  issue_poll(thbuf);   // slot 0, tags pre-zeroed == valid for t=0

  for (int t = 0; t < S_; ++t){
    const unsigned* hp = thbuf + (t & 1) * (B_*H_);
    unsigned*       hn = thbuf + ((t & 1) ^ 1) * (B_*H_);

    // ---- 1. validate in-flight poll; parallel retry rounds (per-lane mask) ----
    {
      const unsigned tag = (unsigned)t & 0xffffu;
      const unsigned long long tmask = 0xffff0000ffff0000ull;
      const unsigned long long texp  = ((unsigned long long)tag << 16)
                                     | ((unsigned long long)tag << 48);
      unsigned stale = 0xffu;
      long rounds = 0;
      while (stale){
        unsigned ns = 0;
        #pragma unroll
        for (int i = 0; i < 8; ++i){
          if (stale & (1u << i)){
            unsigned long long d = ((q[i][0]^texp)|(q[i][1]^texp)
                                   |(q[i][2]^texp)|(q[i][3]^texp)) & tmask;
            if (d != 0ull){
              const unsigned long long* p = (const unsigned long long*)(hp + obase + i*512);
              q[i][0] = ld64a(p);   q[i][1] = ld64a(p+1);
              q[i][2] = ld64a(p+2); q[i][3] = ld64a(p+3);
              ns |= (1u << i);
            }
          }
        }
        stale = ns;
        if (++rounds > (1L<<20)) break;   // safety: never hang the harness
      }
    }

    // ---- 2. extract (v_perm) + hh MFMA (wave reconverged) ----
    #pragma unroll
    for (int i = 0; i < 8; ++i){
      union { unsigned u[4]; bf16x8 v8; } eb;
      #pragma unroll
      for (int w = 0; w < 4; ++w){
        unsigned lo = (unsigned)q[i][w];
        unsigned hi = (unsigned)(q[i][w] >> 32);
        eb.u[w] = __builtin_amdgcn_perm(hi, lo, 0x05040100u);
      }
      #pragma unroll
      for (int mt = 0; mt < 4; ++mt)
        acc[mt] = __builtin_amdgcn_mfma_f32_16x16x32_bf16(whhf[mt][i], eb.v8, acc[mt], 0,0,0);
    }

    // ---- 3. per-wave partials -> LDS (ping-pong, 1 barrier/step) ----
    #pragma unroll
    for (int mt = 0; mt < 4; ++mt)
      #pragma unroll
      for (int r = 0; r < 4; ++r)
        gates_s[t & 1][wave][mt*16 + quad*4 + r][c16] = acc[mt][r];
    __syncthreads();

    // ---- 4. nonlinearity + state update + tagged h store ----
    {
      float gsum[4];
      #pragma unroll
      for (int g = 0; g < 4; ++g){
        float s = bsum[g];
        #pragma unroll
        for (int q2 = 0; q2 < 4; ++q2) s += gates_s[t & 1][q2][g*16 + uu][nn];
        gsum[g] = s;
      }
      float iv = sigm(gsum[0]), fv = sigm(gsum[1]), gv = tanh_(gsum[2]), ov = sigm(gsum[3]);
      float cn = fv*cstate + iv*gv;
      cstate = cn;
      float hv = ov*tanh_(cn);
      unsigned word = (((unsigned)(t+1) & 0xffffu) << 16) | (unsigned)f2b(hv);
      __hip_atomic_store(hn + (size_t)(bg*64 + cg)*256 + tid, word,
                         __ATOMIC_RELAXED, __HIP_MEMORY_SCOPE_AGENT);
      if (t == S_-1){
        out[(bg*16 + nn)*H_ + cg*16 + uu]          = hv;   // h_n
        out[B_*H_ + (bg*16 + nn)*H_ + cg*16 + uu]  = cn;   // c_n
      }
    }

    // ---- 5. PIPELINED: issue poll(t+1) first, THEN xp(t+1) + ldx(t+2) ----
    if (t < S_-1){
      issue_poll(hn);   // first poll RT overlaps xp compute + peer stores
      zacc();
      xp_mfma();        // X(t+1), already resident
      ldx(t + 2);       // in flight across poll(t+1) validation
    }
  }
}

extern "C" void kernel_launch(void* const* d_in, const int* in_sizes, int n_in,
                              void* d_out, int out_size, void* d_ws, size_t ws_size,
                              hipStream_t stream) {
  const float* X   = (const float*)d_in[0];
  const float* Wih = (const float*)d_in[1];
  const float* Whh = (const float*)d_in[2];
  const float* bih = (const float*)d_in[3];
  const float* bhh = (const float*)d_in[4];
  float* out = (float*)d_out;

  // ws layout: [0, 512KB) tagged h double buffer, [512KB, +35.7MB) X bf16.
  char* ws = (char*)d_ws;
  const size_t THBUF_BYTES = 2ull * B_ * H_ * sizeof(unsigned);     // 524288
  const size_t XB_OFF      = THBUF_BYTES;
  const size_t XB_BYTES    = (size_t)B_ * S_ * D_ * sizeof(ushort); // 35.65 MB
  if (ws_size < XB_OFF + XB_BYTES) return;  // insufficient scratch: fail visibly

  unsigned* thbuf = (unsigned*)ws;
  ushort*   Xb    = (ushort*)(ws + XB_OFF);

  hipMemsetAsync(d_ws, 0, THBUF_BYTES, stream);   // tags=0, h0=0

  int n4 = B_*S_*D_/4;
  cvt_x<<<(n4 + 255)/256, 256, 0, stream>>>(X, Xb, n4);
  lstm_persist<<<GRID_, 256, 0, stream>>>(Wih, Whh, bih, bhh, Xb, thbuf, out);
}